// Round 19
// baseline (119.640 us; speedup 1.0000x reference)
//
#include <hip/hip_runtime.h>
#include <math.h>

#define HDIM 256
#define H4   64          // HDIM / 4
#define EPSN 1e-8f       // torch F.cosine_similarity norm clamp
#define CT   128         // c-tile per block = 8 waves x 16-c subtiles; NT=157
#define KC   8           // f4 k-steps per chunk (32 floats)
#define NCH  8           // chunks: KC*NCH = H4
#define QSTR 264         // q LDS row stride in bf16 (528B: 16B-aligned, 2-way banks)

typedef unsigned long long u64;
typedef unsigned int       u32;
typedef __attribute__((ext_vector_type(8))) __bf16 bf16x8;
typedef __attribute__((ext_vector_type(4))) __bf16 bf16x4;
typedef __attribute__((ext_vector_type(4))) float  f32x4;

// Monotonic (value, index) packing: larger key == better candidate under
// lax.top_k semantics (descending value, lower index wins ties).
__device__ __forceinline__ u64 make_key(float v, int idx) {
    u32 u = __float_as_uint(v);
    u ^= (u & 0x80000000u) ? 0xFFFFFFFFu : 0x80000000u;
    return ((u64)u << 32) | (u32)(~idx);
}
__device__ __forceinline__ float key_val(u64 k) {
    u32 u = (u32)(k >> 32);
    u ^= (u & 0x80000000u) ? 0x80000000u : 0xFFFFFFFFu;
    return __uint_as_float(u);
}
__device__ __forceinline__ int key_idx(u64 k) { return (int)(~(u32)k); }

__device__ __forceinline__ void insert8(u64* ls, u64 k) {
    if (k > ls[7]) {
        ls[7] = k;
        #pragma unroll
        for (int j = 7; j > 0; --j)
            if (ls[j] > ls[j-1]) { u64 tmp = ls[j]; ls[j] = ls[j-1]; ls[j-1] = tmp; }
    }
}

// ---------------------------------------------------------------------------
// Kernel 1 (sims, zero-barrier K-loop; R16-identical compute) + TAIL MERGE:
// after the cand store, each tile block arrives at a device-scope counter
// (threadfence-reduction pattern, correctness-validated in R6 phase B).
// The last-arriving block (ticket NT-1) merges all NT x 64 x 8 candidate
// runs with its 512 threads and writes scores_out + top_idx -- replacing
// the separate merge kernel and its launch/drain boundary.
// Block NT: is_compressed layout detection (unchanged, validated r1-18).
// ---------------------------------------------------------------------------
__global__ __launch_bounds__(512)
void sims_kernel(const float4* __restrict__ q4, const float4* __restrict__ emb4,
                 const u32* __restrict__ mask4, u64* __restrict__ cand,
                 int* __restrict__ flags, int* __restrict__ top_idx,
                 float* __restrict__ scores_out, u32* __restrict__ ctr,
                 int C, int B, int NT) {
    const int t = threadIdx.x;

    if (blockIdx.x == (unsigned)NT) {        // ---- mask layout detection ----
        __shared__ int red0[8], red1[8];
        int lo = 0, lg = 0;
        const int n4 = C >> 2;
        int i = t;
        for (; i + 1536 < n4; i += 2048) {
            u32 v0 = mask4[i], v1 = mask4[i + 512], v2 = mask4[i + 1024], v3 = mask4[i + 1536];
            u32 o = v0 | v1 | v2 | v3;
            if (o & 0xFFFFFF00u) lo = 1;   // nonzero byte at offset 1..3
            if (o & 0xFEFEFEFEu) lg = 1;   // any byte value > 1
        }
        for (; i < n4; i += 512) {
            u32 v = mask4[i];
            if (v & 0xFFFFFF00u) lo = 1;
            if (v & 0xFEFEFEFEu) lg = 1;
        }
        const unsigned char* mb = (const unsigned char*)mask4;
        for (int j = (n4 << 2) + t; j < C; j += 512) {
            unsigned char v = mb[j];
            if (v > 1) lg = 1;
            if ((j & 3) != 0 && v != 0) lo = 1;
        }
        lo = __any(lo); lg = __any(lg);
        if ((t & 63) == 0) { red0[t >> 6] = lo; red1[t >> 6] = lg; }
        __syncthreads();
        if (t == 0) {
            int a0 = 0, a1 = 0;
            #pragma unroll
            for (int r = 0; r < 8; ++r) { a0 |= red0[r]; a1 |= red1[r]; }
            flags[0] = a0; flags[1] = a1;
        }
        return;
    }

    __shared__ union {
        struct { __bf16 qh[64][QSTR]; __bf16 ql[64][QSTR]; } st;   // 67.6 KB
        struct { float sc[64][CT + 1]; u64 sp[64][7][8]; } ep;     // 61.7 KB
    } sm;
    __shared__ float qn[64];
    __shared__ float en[CT];
    __shared__ u64   mg[64][8][8];   // 32 KB tail-merge scratch (grid=158 -> 1 blk/CU anyway)
    __shared__ int   last_flag;

    const int c0   = blockIdx.x * CT;
    const int lane = t & 63;
    const int w    = t >> 6;          // wave id = c-subtile
    const int mrow = lane & 15;
    const int kg   = lane >> 4;       // k-group within fragment
    const float4 z = make_float4(0.f, 0.f, 0.f, 0.f);

    // ---- issue e-chunk 0/1 loads first (HBM latency overlaps q staging) ----
    const int  erow = c0 + w * 16 + mrow;
    const bool ev   = erow < C;
    const float4* erp = emb4 + (size_t)erow * H4 + kg * 2;
    float4 cur0 = ev ? erp[0] : z;
    float4 cur1 = ev ? erp[1] : z;
    float4 nxt0 = ev ? erp[KC]     : z;
    float4 nxt1 = ev ? erp[KC + 1] : z;

    // ---- stage q once as hi/lo bf16; q-norms fused (recon, 8-thread reduce) --
    {
        const int r  = t >> 3;         // q row 0..63
        const int c8 = (t & 7) * 8;    // f4 base within row
        float qp = 0.f;
        #pragma unroll
        for (int i = 0; i < 8; ++i) {
            float4 v = (r < B) ? q4[(size_t)r * H4 + c8 + i] : z;
            bf16x4 h, l;
            h.x = (__bf16)v.x; h.y = (__bf16)v.y; h.z = (__bf16)v.z; h.w = (__bf16)v.w;
            l.x = (__bf16)(v.x - (float)h.x); l.y = (__bf16)(v.y - (float)h.y);
            l.z = (__bf16)(v.z - (float)h.z); l.w = (__bf16)(v.w - (float)h.w);
            *(bf16x4*)&sm.st.qh[r][(c8 + i) * 4] = h;
            *(bf16x4*)&sm.st.ql[r][(c8 + i) * 4] = l;
            float x0 = (float)h.x + (float)l.x, x1 = (float)h.y + (float)l.y;
            float x2 = (float)h.z + (float)l.z, x3 = (float)h.w + (float)l.w;
            qp = fmaf(x0, x0, fmaf(x1, x1, fmaf(x2, x2, fmaf(x3, x3, qp))));
        }
        qp += __shfl_xor(qp, 1, 64);
        qp += __shfl_xor(qp, 2, 64);
        qp += __shfl_xor(qp, 4, 64);
        if ((t & 7) == 0) qn[r] = 1.f / fmaxf(sqrtf(qp), EPSN);
    }
    __syncthreads();               // q LDS + qn ready; NO barriers in K-loop

    // ---- zero-barrier K-loop (identical to R16) ----
    f32x4 acc[4];
    #pragma unroll
    for (int m = 0; m < 4; ++m) acc[m] = (f32x4){0.f, 0.f, 0.f, 0.f};
    float epart = 0.f;

    #pragma unroll
    for (int ch = 0; ch < NCH; ++ch) {
        float4 n20 = z, n21 = z;
        if (ch + 2 < NCH) {            // 2-deep register prefetch
            n20 = ev ? erp[(ch + 2) * KC]     : z;
            n21 = ev ? erp[(ch + 2) * KC + 1] : z;
        }
        bf16x8 bh, bl;
        {
            float xs[8] = {cur0.x, cur0.y, cur0.z, cur0.w,
                           cur1.x, cur1.y, cur1.z, cur1.w};
            #pragma unroll
            for (int i = 0; i < 8; ++i) {
                __bf16 h = (__bf16)xs[i];
                __bf16 l = (__bf16)(xs[i] - (float)h);
                bh[i] = h; bl[i] = l;
                float x = (float)h + (float)l;
                epart = fmaf(x, x, epart);
            }
        }
        #pragma unroll
        for (int m = 0; m < 4; ++m) {
            bf16x8 ah = *(const bf16x8*)&sm.st.qh[m * 16 + mrow][ch * 32 + kg * 8];
            bf16x8 al = *(const bf16x8*)&sm.st.ql[m * 16 + mrow][ch * 32 + kg * 8];
            acc[m] = __builtin_amdgcn_mfma_f32_16x16x32_bf16(ah, bh, acc[m], 0, 0, 0);
            acc[m] = __builtin_amdgcn_mfma_f32_16x16x32_bf16(ah, bl, acc[m], 0, 0, 0);
            acc[m] = __builtin_amdgcn_mfma_f32_16x16x32_bf16(al, bh, acc[m], 0, 0, 0);
        }
        cur0 = nxt0; cur1 = nxt1;
        nxt0 = n20;  nxt1 = n21;
    }

    // ---- e-norms (reduce kg groups) ----
    epart += __shfl_xor(epart, 16, 64);
    epart += __shfl_xor(epart, 32, 64);
    if (kg == 0) en[w * 16 + mrow] = 1.f / fmaxf(sqrtf(epart), EPSN);

    __syncthreads();               // all waves done with q LDS; en visible

    // ---- scores -> LDS: D[b = m*16+kg*4+r][c = w*16+mrow] ----
    const float ev2 = en[w * 16 + mrow];
    #pragma unroll
    for (int m = 0; m < 4; ++m) {
        #pragma unroll
        for (int r = 0; r < 4; ++r) {
            int b = m * 16 + kg * 4 + r;
            sm.ep.sc[b][w * 16 + mrow] = acc[m][r] * qn[b] * ev2;
        }
    }
    __syncthreads();

    // ---- per-(b,tile) top-8 + contiguous store (identical to R16) ----
    const int sb = t & 63;         // b
    const int g  = t >> 6;         // c-group (16 c's each)
    u64 ls[8];
    #pragma unroll
    for (int j = 0; j < 8; ++j) ls[j] = 0ull;
    #pragma unroll
    for (int i2 = 0; i2 < 16; ++i2) {
        int cl = g * 16 + i2;
        int c  = c0 + cl;
        if (c < C && sb < B) insert8(ls, make_key(sm.ep.sc[sb][cl], c));
    }
    if (g != 0) {                  // sp disjoint from sc: no alias hazard
        #pragma unroll
        for (int r = 0; r < 8; ++r) sm.ep.sp[sb][g - 1][r] = ls[r];
    }
    __syncthreads();
    if (g == 0) {                  // wave 0: merge 8x8 -> 8, contiguous store
        #pragma unroll
        for (int gg = 0; gg < 7; ++gg)
            #pragma unroll
            for (int r = 0; r < 8; ++r) insert8(ls, sm.ep.sp[sb][gg][r]);
        u64* dst = cand + (((size_t)blockIdx.x * 64) + sb) * 8;
        #pragma unroll
        for (int r = 0; r < 8; ++r) dst[r] = ls[r];
    }

    // ---- arrival: threadfence-reduction handoff (R6-validated pattern) ----
    __threadfence();               // publish this block's cand stores
    __syncthreads();
    if (t == 0) {
        u32 ticket = __hip_atomic_fetch_add(ctr, 1u, __ATOMIC_ACQ_REL,
                                            __HIP_MEMORY_SCOPE_AGENT);
        last_flag = (ticket == (u32)(NT - 1));
    }
    __syncthreads();
    if (!last_flag) return;

    // ================= TAIL MERGE (last block only, 512 threads) ===========
    __threadfence();               // acquire: invalidate stale lines before
                                   // reading other blocks' cand
    {
        const int mb2 = t >> 3;    // b 0..63
        const int mh  = t & 7;     // run-group: tiles mh, mh+8, ...
        u64 ms[8];
        #pragma unroll
        for (int r = 0; r < 8; ++r) ms[r] = 0ull;

        #define PROCESS(tt, kf) do {                                          \
            if ((kf) > ms[7]) {                                               \
                const u64* rp = cand + (((size_t)(tt)) * 64 + mb2) * 8;       \
                u64 kk = (kf);                                                \
                int rr = 1;                                                   \
                while (1) {                                                   \
                    ms[7] = kk;                                               \
                    _Pragma("unroll")                                         \
                    for (int q = 7; q > 0; --q)                               \
                        if (ms[q] > ms[q-1]) { u64 tm = ms[q]; ms[q] = ms[q-1]; ms[q-1] = tm; } \
                    if (rr >= 8) break;                                       \
                    kk = rp[rr++];                                            \
                    if (kk <= ms[7]) break;                                   \
                }                                                             \
            }                                                                 \
        } while (0)

        int tile = mh;
        for (; tile + 24 < NT; tile += 32) {   // 4 first-keys batched (MLP)
            u64 k0 = cand[(((size_t)tile)      * 64 + mb2) * 8];
            u64 k1 = cand[(((size_t)tile + 8)  * 64 + mb2) * 8];
            u64 k2 = cand[(((size_t)tile + 16) * 64 + mb2) * 8];
            u64 k3 = cand[(((size_t)tile + 24) * 64 + mb2) * 8];
            PROCESS(tile,      k0);
            PROCESS(tile + 8,  k1);
            PROCESS(tile + 16, k2);
            PROCESS(tile + 24, k3);
        }
        for (; tile < NT; tile += 8) {
            u64 kf = cand[(((size_t)tile) * 64 + mb2) * 8];
            PROCESS(tile, kf);
        }
        #undef PROCESS

        #pragma unroll
        for (int r = 0; r < 8; ++r) mg[mb2][mh][r] = ms[r];
    }
    __syncthreads();
    if (t < 64) {                  // thread t = b: merge 8 sorted runs of 8
        u64 fs[8];
        #pragma unroll
        for (int r = 0; r < 8; ++r) fs[r] = 0ull;
        #pragma unroll
        for (int hh = 0; hh < 8; ++hh) {
            #pragma unroll
            for (int r = 0; r < 8; ++r) {
                u64 k = mg[t][hh][r];
                if (k <= fs[7]) break;          // runs sorted descending
                fs[7] = k;
                #pragma unroll
                for (int q = 7; q > 0; --q)
                    if (fs[q] > fs[q-1]) { u64 tm = fs[q]; fs[q] = fs[q-1]; fs[q-1] = tm; }
            }
        }
        #pragma unroll
        for (int r = 0; r < 8; ++r) {
            scores_out[t * 8 + r] = key_val(fs[r]);
            top_idx[t * 8 + r]    = key_idx(fs[r]);
        }
    }
}

// ---------------------------------------------------------------------------
// Kernel 2 (gather): identical to round 16.
// ---------------------------------------------------------------------------
__global__ __launch_bounds__(256)
void gather_kernel(const float* __restrict__ episodes,    // [C][S][256]
                   const float* __restrict__ compressed,  // [C][Cs][256]
                   const void* __restrict__ is_comp,
                   const int* __restrict__ top_idx,       // [B*8]
                   const int* __restrict__ flags,
                   float* __restrict__ out,               // [B*8][S*256]
                   int S, int Cs) {
    const int bj  = blockIdx.x >> 1;
    const int h   = blockIdx.x & 1;
    const int idx = top_idx[bj];
    const int f_off = flags[0], f_gt1 = flags[1];

    bool comp;
    if      (f_gt1) comp = ((const float*)is_comp)[idx] != 0.f;
    else if (f_off) comp = ((const unsigned char*)is_comp)[idx] != 0;
    else            comp = ((const int*)is_comp)[idx] != 0;

    const int n4   = S * H4;       // 2048
    const int c4   = Cs * H4;      // 1024
    const int half = n4 >> 1;      // 1024
    const int v0   = h * half;

    const float4* full4 = (const float4*)episodes   + (size_t)idx * n4;
    const float4* cmp4  = (const float4*)compressed + (size_t)idx * c4;
    float4* out4 = (float4*)out + (size_t)bj * n4;
    const float4 z = make_float4(0.f, 0.f, 0.f, 0.f);

    if (comp) {
        #pragma unroll 4
        for (int v = v0 + threadIdx.x; v < v0 + half; v += 256)
            out4[v] = (v < c4) ? cmp4[v] : z;
    } else {
        #pragma unroll 4
        for (int v = v0 + threadIdx.x; v < v0 + half; v += 256)
            out4[v] = full4[v];
    }
}

// ---------------------------------------------------------------------------
extern "C" void kernel_launch(void* const* d_in, const int* in_sizes, int n_in,
                              void* d_out, int out_size, void* d_ws, size_t ws_size,
                              hipStream_t stream) {
    const float* query      = (const float*)d_in[0];
    const float* episodes   = (const float*)d_in[1];
    const float* compressed = (const float*)d_in[2];
    const float* emb        = (const float*)d_in[3];
    const void*  is_comp    = d_in[4];
    // d_in[5] is k (device scalar); fixed at 8 by the problem setup.

    const int B  = in_sizes[0] / HDIM;        // 64
    const int C  = in_sizes[3] / HDIM;        // 20000
    const int S  = in_sizes[1] / (C * HDIM);  // 32
    const int Cs = in_sizes[2] / (C * HDIM);  // 16
    const int K  = 8;
    const int NT = (C + CT - 1) / CT;         // 157

    float* out        = (float*)d_out;
    float* scores_out = out + (size_t)B * K * S * HDIM;

    // scratch layout in d_ws (ctr memset each call -> replay-safe; rest
    // fully rewritten every call -> deterministic):
    u32*  ctr     = (u32*)d_ws;                          // 1 u32 (zeroed)
    int*  flags   = (int*)((char*)d_ws + 16);            // 2 ints
    int*  top_idx = (int*)((char*)d_ws + 64);            // B*K ints
    u64*  cand    = (u64*)((char*)d_ws + 4096);          // NT*64*8 u64 = 0.64 MB

    hipMemsetAsync(d_ws, 0, 16, stream);
    sims_kernel<<<NT + 1, 512, 0, stream>>>(
        (const float4*)query, (const float4*)emb, (const u32*)is_comp,
        cand, flags, top_idx, scores_out, ctr, C, B, NT);
    gather_kernel<<<B * K * 2, 256, 0, stream>>>(episodes, compressed, is_comp,
                                                 top_idx, flags, out, S, Cs);
}

// Round 20
// 46.648 us; speedup vs baseline: 2.5648x; 2.5648x over previous
//
#include <hip/hip_runtime.h>
#include <math.h>

#define HDIM 256
#define H4   64          // HDIM / 4
#define EPSN 1e-8f       // torch F.cosine_similarity norm clamp
#define CT   128         // c-tile per block = 8 waves x 16-c subtiles; NT=157
#define KC   8           // f4 k-steps per chunk (32 floats)
#define NCH  8           // chunks: KC*NCH = H4
#define QSTR 264         // q LDS row stride in bf16 (528B: 16B-aligned, 2-way banks)

typedef unsigned long long u64;
typedef unsigned int       u32;
typedef __attribute__((ext_vector_type(8))) __bf16 bf16x8;
typedef __attribute__((ext_vector_type(4))) __bf16 bf16x4;
typedef __attribute__((ext_vector_type(4))) float  f32x4;

// Monotonic (value, index) packing: larger key == better candidate under
// lax.top_k semantics (descending value, lower index wins ties).
__device__ __forceinline__ u64 make_key(float v, int idx) {
    u32 u = __float_as_uint(v);
    u ^= (u & 0x80000000u) ? 0xFFFFFFFFu : 0x80000000u;
    return ((u64)u << 32) | (u32)(~idx);
}
__device__ __forceinline__ float key_val(u64 k) {
    u32 u = (u32)(k >> 32);
    u ^= (u & 0x80000000u) ? 0x80000000u : 0xFFFFFFFFu;
    return __uint_as_float(u);
}
__device__ __forceinline__ int key_idx(u64 k) { return (int)(~(u32)k); }

__device__ __forceinline__ void insert8(u64* ls, u64 k) {
    if (k > ls[7]) {
        ls[7] = k;
        #pragma unroll
        for (int j = 7; j > 0; --j)
            if (ls[j] > ls[j-1]) { u64 tmp = ls[j]; ls[j] = ls[j-1]; ls[j-1] = tmp; }
    }
}

// ---------------------------------------------------------------------------
// Kernel 1 (sims, zero-barrier K-loop): identical to round 16 (measured best).
// ---------------------------------------------------------------------------
__global__ __launch_bounds__(512)
void sims_kernel(const float4* __restrict__ q4, const float4* __restrict__ emb4,
                 const u32* __restrict__ mask4, u64* __restrict__ cand,
                 int* __restrict__ flags, int C, int B, int NT) {
    const int t = threadIdx.x;

    if (blockIdx.x == (unsigned)NT) {        // ---- mask layout detection ----
        __shared__ int red0[8], red1[8];
        int lo = 0, lg = 0;
        const int n4 = C >> 2;
        int i = t;
        for (; i + 1536 < n4; i += 2048) {
            u32 v0 = mask4[i], v1 = mask4[i + 512], v2 = mask4[i + 1024], v3 = mask4[i + 1536];
            u32 o = v0 | v1 | v2 | v3;
            if (o & 0xFFFFFF00u) lo = 1;   // nonzero byte at offset 1..3
            if (o & 0xFEFEFEFEu) lg = 1;   // any byte value > 1
        }
        for (; i < n4; i += 512) {
            u32 v = mask4[i];
            if (v & 0xFFFFFF00u) lo = 1;
            if (v & 0xFEFEFEFEu) lg = 1;
        }
        const unsigned char* mb = (const unsigned char*)mask4;
        for (int j = (n4 << 2) + t; j < C; j += 512) {
            unsigned char v = mb[j];
            if (v > 1) lg = 1;
            if ((j & 3) != 0 && v != 0) lo = 1;
        }
        lo = __any(lo); lg = __any(lg);
        if ((t & 63) == 0) { red0[t >> 6] = lo; red1[t >> 6] = lg; }
        __syncthreads();
        if (t == 0) {
            int a0 = 0, a1 = 0;
            #pragma unroll
            for (int r = 0; r < 8; ++r) { a0 |= red0[r]; a1 |= red1[r]; }
            flags[0] = a0; flags[1] = a1;
        }
        return;
    }

    __shared__ union {
        struct { __bf16 qh[64][QSTR]; __bf16 ql[64][QSTR]; } st;   // 67.6 KB
        struct { float sc[64][CT + 1]; u64 sp[64][7][8]; } ep;     // 61.7 KB
    } sm;
    __shared__ float qn[64];
    __shared__ float en[CT];

    const int c0   = blockIdx.x * CT;
    const int lane = t & 63;
    const int w    = t >> 6;          // wave id = c-subtile
    const int mrow = lane & 15;
    const int kg   = lane >> 4;       // k-group within fragment
    const float4 z = make_float4(0.f, 0.f, 0.f, 0.f);

    // ---- issue e-chunk 0/1 loads first (HBM latency overlaps q staging) ----
    const int  erow = c0 + w * 16 + mrow;
    const bool ev   = erow < C;
    const float4* erp = emb4 + (size_t)erow * H4 + kg * 2;
    float4 cur0 = ev ? erp[0] : z;
    float4 cur1 = ev ? erp[1] : z;
    float4 nxt0 = ev ? erp[KC]     : z;
    float4 nxt1 = ev ? erp[KC + 1] : z;

    // ---- stage q once as hi/lo bf16; q-norms fused (recon, 8-thread reduce) --
    {
        const int r  = t >> 3;         // q row 0..63
        const int c8 = (t & 7) * 8;    // f4 base within row
        float qp = 0.f;
        #pragma unroll
        for (int i = 0; i < 8; ++i) {
            float4 v = (r < B) ? q4[(size_t)r * H4 + c8 + i] : z;
            bf16x4 h, l;
            h.x = (__bf16)v.x; h.y = (__bf16)v.y; h.z = (__bf16)v.z; h.w = (__bf16)v.w;
            l.x = (__bf16)(v.x - (float)h.x); l.y = (__bf16)(v.y - (float)h.y);
            l.z = (__bf16)(v.z - (float)h.z); l.w = (__bf16)(v.w - (float)h.w);
            *(bf16x4*)&sm.st.qh[r][(c8 + i) * 4] = h;
            *(bf16x4*)&sm.st.ql[r][(c8 + i) * 4] = l;
            float x0 = (float)h.x + (float)l.x, x1 = (float)h.y + (float)l.y;
            float x2 = (float)h.z + (float)l.z, x3 = (float)h.w + (float)l.w;
            qp = fmaf(x0, x0, fmaf(x1, x1, fmaf(x2, x2, fmaf(x3, x3, qp))));
        }
        qp += __shfl_xor(qp, 1, 64);
        qp += __shfl_xor(qp, 2, 64);
        qp += __shfl_xor(qp, 4, 64);
        if ((t & 7) == 0) qn[r] = 1.f / fmaxf(sqrtf(qp), EPSN);
    }
    __syncthreads();               // q LDS + qn ready; NO barriers after this

    // ---- zero-barrier K-loop ----
    f32x4 acc[4];
    #pragma unroll
    for (int m = 0; m < 4; ++m) acc[m] = (f32x4){0.f, 0.f, 0.f, 0.f};
    float epart = 0.f;

    #pragma unroll
    for (int ch = 0; ch < NCH; ++ch) {
        float4 n20 = z, n21 = z;
        if (ch + 2 < NCH) {            // 2-deep register prefetch
            n20 = ev ? erp[(ch + 2) * KC]     : z;
            n21 = ev ? erp[(ch + 2) * KC + 1] : z;
        }
        // convert this chunk's e slice to hi/lo bf16; e-norm partial (recon)
        bf16x8 bh, bl;
        {
            float xs[8] = {cur0.x, cur0.y, cur0.z, cur0.w,
                           cur1.x, cur1.y, cur1.z, cur1.w};
            #pragma unroll
            for (int i = 0; i < 8; ++i) {
                __bf16 h = (__bf16)xs[i];
                __bf16 l = (__bf16)(xs[i] - (float)h);
                bh[i] = h; bl[i] = l;
                float x = (float)h + (float)l;
                epart = fmaf(x, x, epart);
            }
        }
        #pragma unroll
        for (int m = 0; m < 4; ++m) {
            bf16x8 ah = *(const bf16x8*)&sm.st.qh[m * 16 + mrow][ch * 32 + kg * 8];
            bf16x8 al = *(const bf16x8*)&sm.st.ql[m * 16 + mrow][ch * 32 + kg * 8];
            acc[m] = __builtin_amdgcn_mfma_f32_16x16x32_bf16(ah, bh, acc[m], 0, 0, 0);
            acc[m] = __builtin_amdgcn_mfma_f32_16x16x32_bf16(ah, bl, acc[m], 0, 0, 0);
            acc[m] = __builtin_amdgcn_mfma_f32_16x16x32_bf16(al, bh, acc[m], 0, 0, 0);
        }
        cur0 = nxt0; cur1 = nxt1;
        nxt0 = n20;  nxt1 = n21;
    }

    // ---- e-norms (reduce kg groups) ----
    epart += __shfl_xor(epart, 16, 64);
    epart += __shfl_xor(epart, 32, 64);
    if (kg == 0) en[w * 16 + mrow] = 1.f / fmaxf(sqrtf(epart), EPSN);

    __syncthreads();               // all waves done with q LDS; en visible

    // ---- scores -> LDS: D[b = m*16+kg*4+r][c = w*16+mrow] ----
    const float ev2 = en[w * 16 + mrow];
    #pragma unroll
    for (int m = 0; m < 4; ++m) {
        #pragma unroll
        for (int r = 0; r < 4; ++r) {
            int b = m * 16 + kg * 4 + r;
            sm.ep.sc[b][w * 16 + mrow] = acc[m][r] * qn[b] * ev2;
        }
    }
    __syncthreads();

    // ---- per-(b,tile) top-8 + contiguous store (R14/R15 pattern, 8 groups) --
    const int sb = t & 63;         // b
    const int g  = t >> 6;         // c-group (16 c's each)
    u64 ls[8];
    #pragma unroll
    for (int j = 0; j < 8; ++j) ls[j] = 0ull;
    #pragma unroll
    for (int i2 = 0; i2 < 16; ++i2) {
        int cl = g * 16 + i2;
        int c  = c0 + cl;
        if (c < C && sb < B) insert8(ls, make_key(sm.ep.sc[sb][cl], c));
    }
    if (g != 0) {                  // sp disjoint from sc: no alias hazard
        #pragma unroll
        for (int r = 0; r < 8; ++r) sm.ep.sp[sb][g - 1][r] = ls[r];
    }
    __syncthreads();
    if (g == 0) {                  // wave 0: merge 8x8 -> 8, contiguous store
        #pragma unroll
        for (int gg = 0; gg < 7; ++gg)
            #pragma unroll
            for (int r = 0; r < 8; ++r) insert8(ls, sm.ep.sp[sb][gg][r]);
        u64* dst = cand + (((size_t)blockIdx.x * 64) + sb) * 8;
        #pragma unroll
        for (int r = 0; r < 8; ++r) dst[r] = ls[r];
    }
}

// ---------------------------------------------------------------------------
// Kernel 2 (merge): identical to round 16.
// ---------------------------------------------------------------------------
__global__ __launch_bounds__(256)
void merge_kernel(const u64* __restrict__ cand,
                  float* __restrict__ scores_out, int* __restrict__ top_idx,
                  int B, int NT) {
    __shared__ u64 sh[256 * 8];   // 16 KB
    const int b = blockIdx.x, t = threadIdx.x;

    u64 ls[8];
    #pragma unroll
    for (int j = 0; j < 8; ++j) ls[j] = 0ull;

    for (int tile = t; tile < NT; tile += 256) {
        const u64* pp = cand + (((size_t)tile * 64) + b) * 8;
        #pragma unroll
        for (int r = 0; r < 8; ++r) {
            u64 k = pp[r];
            if (k <= ls[7]) break;          // pp[] sorted descending
            ls[7] = k;
            #pragma unroll
            for (int q = 7; q > 0; --q)
                if (ls[q] > ls[q-1]) { u64 tmp = ls[q]; ls[q] = ls[q-1]; ls[q-1] = tmp; }
        }
    }

    #pragma unroll
    for (int j = 0; j < 8; ++j) sh[t * 8 + j] = ls[j];
    __syncthreads();

    if (t < 64) {
        u64 m[8];
        #pragma unroll
        for (int j = 0; j < 8; ++j) m[j] = 0ull;
        for (int tt = 0; tt < 4; ++tt) {
            const u64* pp = &sh[(t * 4 + tt) * 8];
            #pragma unroll
            for (int j = 0; j < 8; ++j) {
                u64 k = pp[j];
                if (k <= m[7]) break;           // pp[] sorted descending
                m[7] = k;
                #pragma unroll
                for (int q = 7; q > 0; --q)
                    if (m[q] > m[q-1]) { u64 tmp = m[q]; m[q] = m[q-1]; m[q-1] = tmp; }
            }
        }
        for (int r = 0; r < 8; ++r) {
            u64 best = m[0];
            #pragma unroll
            for (int off = 32; off; off >>= 1) {
                u64 o = __shfl_xor(best, off, 64);
                if (o > best) best = o;
            }
            if (m[0] == best) {                 // unique owner pops
                #pragma unroll
                for (int q = 0; q < 7; ++q) m[q] = m[q+1];
                m[7] = 0ull;
            }
            if (t == 0) {
                scores_out[b * 8 + r] = key_val(best);
                top_idx[b * 8 + r]    = key_idx(best);
            }
        }
    }
}

// ---------------------------------------------------------------------------
// Kernel 3 (gather): identical to round 16.
// ---------------------------------------------------------------------------
__global__ __launch_bounds__(256)
void gather_kernel(const float* __restrict__ episodes,    // [C][S][256]
                   const float* __restrict__ compressed,  // [C][Cs][256]
                   const void* __restrict__ is_comp,
                   const int* __restrict__ top_idx,       // [B*8]
                   const int* __restrict__ flags,
                   float* __restrict__ out,               // [B*8][S*256]
                   int S, int Cs) {
    const int bj  = blockIdx.x >> 1;
    const int h   = blockIdx.x & 1;
    const int idx = top_idx[bj];
    const int f_off = flags[0], f_gt1 = flags[1];

    bool comp;
    if      (f_gt1) comp = ((const float*)is_comp)[idx] != 0.f;
    else if (f_off) comp = ((const unsigned char*)is_comp)[idx] != 0;
    else            comp = ((const int*)is_comp)[idx] != 0;

    const int n4   = S * H4;       // 2048
    const int c4   = Cs * H4;      // 1024
    const int half = n4 >> 1;      // 1024
    const int v0   = h * half;

    const float4* full4 = (const float4*)episodes   + (size_t)idx * n4;
    const float4* cmp4  = (const float4*)compressed + (size_t)idx * c4;
    float4* out4 = (float4*)out + (size_t)bj * n4;
    const float4 z = make_float4(0.f, 0.f, 0.f, 0.f);

    if (comp) {
        #pragma unroll 4
        for (int v = v0 + threadIdx.x; v < v0 + half; v += 256)
            out4[v] = (v < c4) ? cmp4[v] : z;
    } else {
        #pragma unroll 4
        for (int v = v0 + threadIdx.x; v < v0 + half; v += 256)
            out4[v] = full4[v];
    }
}

// ---------------------------------------------------------------------------
extern "C" void kernel_launch(void* const* d_in, const int* in_sizes, int n_in,
                              void* d_out, int out_size, void* d_ws, size_t ws_size,
                              hipStream_t stream) {
    const float* query      = (const float*)d_in[0];
    const float* episodes   = (const float*)d_in[1];
    const float* compressed = (const float*)d_in[2];
    const float* emb        = (const float*)d_in[3];
    const void*  is_comp    = d_in[4];
    // d_in[5] is k (device scalar); fixed at 8 by the problem setup.

    const int B  = in_sizes[0] / HDIM;        // 64
    const int C  = in_sizes[3] / HDIM;        // 20000
    const int S  = in_sizes[1] / (C * HDIM);  // 32
    const int Cs = in_sizes[2] / (C * HDIM);  // 16
    const int K  = 8;
    const int NT = (C + CT - 1) / CT;         // 157

    float* out        = (float*)d_out;
    float* scores_out = out + (size_t)B * K * S * HDIM;

    // scratch layout in d_ws (fully rewritten every call -> deterministic):
    u64*  cand    = (u64*)d_ws;                          // NT*64*8 u64 = 0.64 MB
    int*  top_idx = (int*)(cand + (size_t)NT * 64 * 8);  // B*K ints
    int*  flags   = top_idx + B * K;                     // 2 ints

    sims_kernel<<<NT + 1, 512, 0, stream>>>(
        (const float4*)query, (const float4*)emb, (const u32*)is_comp,
        cand, flags, C, B, NT);
    merge_kernel<<<B, 256, 0, stream>>>(cand, scores_out, top_idx, B, NT);
    gather_kernel<<<B * K * 2, 256, 0, stream>>>(episodes, compressed, is_comp,
                                                 top_idx, flags, out, S, Cs);
}